// Round 5
// baseline (261.271 us; speedup 1.0000x reference)
//
#include <hip/hip_runtime.h>

// N=50000, E=800000, Q=200000, d_in=64, h=128
// bf16 random-access features; split-bf16 MFMA; atomic-free CSR build (HB=64);
// fusions: hist+xb+fold (k_pre); reduce+scan1 (k_rs); gather1+mfma1 (k_conv1);
//          gather2+mfmaUV (k_conv2). conv1: 4-edge unroll. conv2: 16 nodes/block,
//          2x16-lane half-groups per node (stride-2 edges, shfl_xor combine) --
//          halves serial chain depth, doubles independent load chains.

#define HB 64       // histogram / fill chunks
#define NWIN 16384  // node/word window (64KB LDS)

typedef __attribute__((ext_vector_type(8))) short short8;
typedef __attribute__((ext_vector_type(4))) float floatx4;

static __device__ __forceinline__ unsigned int f2bf(float v) {
    union { float f; unsigned int u; } c; c.f = v;
    unsigned int lsb = (c.u >> 16) & 1u;
    c.u += 0x7FFFu + lsb;                 // round-to-nearest-even
    return c.u >> 16;
}
static __device__ __forceinline__ float bf2f(unsigned int h) {
    union { float f; unsigned int u; } c; c.u = h << 16;
    return c.f;
}

// ---------- fused prologue: histogram + x->bf16 + weight fold/pack ----------
__global__ __launch_bounds__(256) void k_pre(const int* __restrict__ row,
                                             const int* __restrict__ col,
                                             unsigned int* __restrict__ hRow,
                                             unsigned int* __restrict__ hCol,
                                             const float* __restrict__ x,
                                             unsigned int* __restrict__ xb,
                                             const float* __restrict__ W1,
                                             const float* __restrict__ W2,
                                             const float* __restrict__ Wc1,
                                             const float* __restrict__ b2,
                                             const float* __restrict__ bc1,
                                             unsigned short* __restrict__ UVhi,
                                             unsigned short* __restrict__ UVlo,
                                             unsigned short* __restrict__ W1hi,
                                             unsigned short* __restrict__ W1lo,
                                             float* __restrict__ buv,
                                             int E, int N, int W, int chunk,
                                             int nHist, int nXb) {
    __shared__ unsigned int lds[NWIN];
    int t = threadIdx.x, b = blockIdx.x;
    if (b < nHist) {
        int hb = b % HB;
        int yb = b / HB;
        int p = yb >> 1, win = yb & 1;
        int base = win * NWIN;
        int wcap = min(W - base, NWIN);
        if (wcap <= 0) return;
        const int* idxArr = p ? col : row;
        unsigned int* outArr = p ? hCol : hRow;
        int e0 = hb * chunk, e1 = min(E, e0 + chunk);
        for (int i = t; i < wcap; i += 256) lds[i] = 0;
        __syncthreads();
        for (int e = e0 + t; e < e1; e += 256) {
            int idx = idxArr[e];
            int w = (idx >> 1) - base;
            if ((unsigned)w < (unsigned)wcap)
                atomicAdd(&lds[w], 1u << ((idx & 1) * 16));
        }
        __syncthreads();
        for (int i = t; i < wcap; i += 256)
            outArr[(size_t)hb * W + base + i] = lds[i];
    } else if (b < nHist + nXb) {
        int i = (b - nHist) * 256 + t;
        if (i < N * 32) {
            float2 v = ((const float2*)x)[i];
            xb[i] = f2bf(v.x) | (f2bf(v.y) << 16);
        }
    } else {
        int bf = b - nHist - nXb;
        float* w2row = (float*)lds;
        if (bf < 128) {
            int k = bf;
            int j = t & 127, half = t >> 7;
            int n = half * 128 + j;
            const float* wc = Wc1 + (size_t)half * 128 * 128 + j;
            if (t < 128) w2row[t] = W2[k * 128 + t];
            __syncthreads();
            float acc = 0.f;
#pragma unroll 8
            for (int m = 0; m < 128; m++) acc += w2row[m] * wc[(size_t)m * 128];
            int kstep = k >> 5, kl = k & 31, quad = kl >> 3, j8 = kl & 7;
            int nb = n >> 4, l = quad * 16 + (n & 15);
            int pidx = ((kstep * 16 + nb) * 64 + l) * 8 + j8;
            unsigned int h = f2bf(acc);
            UVhi[pidx] = (unsigned short)h;
            UVlo[pidx] = (unsigned short)f2bf(acc - bf2f(h));
        } else if (bf == 128) {
            int j = t & 127, half = t >> 7;
            const float* wc = Wc1 + (size_t)half * 128 * 128 + j;
            float acc = half ? 0.f : bc1[j];
#pragma unroll 8
            for (int m = 0; m < 128; m++) acc += b2[m] * wc[(size_t)m * 128];
            buv[half * 128 + j] = acc;
        } else {
            int idx = (bf - 129) * 256 + t;  // < 8192
            int k = idx >> 7, n = idx & 127;
            float v = W1[k * 128 + n];
            int kstep = k >> 5, kl = k & 31, quad = kl >> 3, j8 = kl & 7;
            int nb = n >> 4, l = quad * 16 + (n & 15);
            int pidx = ((kstep * 8 + nb) * 64 + l) * 8 + j8;
            unsigned int h = f2bf(v);
            W1hi[pidx] = (unsigned short)h;
            W1lo[pidx] = (unsigned short)f2bf(v - bf2f(h));
        }
    }
}

// ---------- fused reduce + block-local scan ----------
__global__ __launch_bounds__(256) void k_rs(const unsigned int* __restrict__ hRow,
                                            unsigned int* __restrict__ hCol,
                                            float* __restrict__ dis,
                                            int* __restrict__ offs,
                                            int* __restrict__ bsum,
                                            int N, int W) {
    __shared__ int ts[256];
    int t = threadIdx.x;
    int w = blockIdx.x * 256 + t;
    unsigned int r0 = 0, r1 = 0, c0 = 0, c1 = 0;
    if (w < W) {
#pragma unroll 8
        for (int b = 0; b < HB; b++) {
            size_t idx = (size_t)b * W + w;
            unsigned int hr = hRow[idx];
            unsigned int hc = hCol[idx];
            hCol[idx] = c0 | (c1 << 16);   // exclusive prefix over blocks
            r0 += hr & 0xFFFFu; r1 += hr >> 16;
            c0 += hc & 0xFFFFu; c1 += hc >> 16;
        }
        int n0 = 2 * w, n1 = 2 * w + 1;
        dis[n0] = 1.0f / sqrtf((float)(r0 + 1));
        if (n1 < N) dis[n1] = 1.0f / sqrtf((float)(r1 + 1));
    }
    int sum = (w < W) ? (int)(c0 + c1) : 0;
    ts[t] = sum;
    __syncthreads();
    for (int off = 1; off < 256; off <<= 1) {
        int xv = (t >= off) ? ts[t - off] : 0;
        __syncthreads();
        ts[t] += xv;
        __syncthreads();
    }
    int e = ts[t] - sum;  // exclusive within block
    if (w < W) {
        int n0 = 2 * w, n1 = 2 * w + 1;
        offs[n0] = e;
        if (n1 < N) offs[n1] = e + (int)c0;
    }
    if (t == 255) bsum[blockIdx.x] = ts[255];
}

__global__ __launch_bounds__(256) void k_scan2(int* __restrict__ bsum, int B) {
    __shared__ int ts[256];
    int t = threadIdx.x;
    int v = (t < B) ? bsum[t] : 0;
    ts[t] = v;
    __syncthreads();
    for (int off = 1; off < 256; off <<= 1) {
        int x = (t >= off) ? ts[t - off] : 0;
        __syncthreads();
        ts[t] += x;
        __syncthreads();
    }
    if (t < B) bsum[t] = ts[t] - v;
}

// each k_rs block covered 512 nodes -> bsum index = i >> 9
__global__ __launch_bounds__(256) void k_scan3(int* __restrict__ offs,
                                               const int* __restrict__ bsum,
                                               int N, int E) {
    int i = blockIdx.x * 256 + threadIdx.x;
    if (i < N) offs[i] = offs[i] + bsum[i >> 9];
    if (i == 0) offs[N] = E;
}

// ---------- CSR fill, atomic-free, 2D grid ----------
__global__ __launch_bounds__(256) void k_fill3(const int* __restrict__ row,
                                               const int* __restrict__ col,
                                               const int* __restrict__ offs,
                                               const unsigned int* __restrict__ hCol,
                                               int* __restrict__ srcSorted,
                                               int E, int N, int W, int chunk) {
    __shared__ int base[NWIN];
    int t = threadIdx.x, b = blockIdx.x;
    int n0 = blockIdx.y * NWIN;
    int nCnt = min(NWIN, N - n0);
    int e0 = b * chunk, e1 = min(E, e0 + chunk);
    for (int wl = t; wl * 2 < nCnt; wl += 256) {
        unsigned int pref = hCol[(size_t)b * W + (n0 >> 1) + wl];
        int nn = n0 + wl * 2;
        base[wl * 2] = offs[nn] + (int)(pref & 0xFFFFu);
        if (wl * 2 + 1 < nCnt)
            base[wl * 2 + 1] = offs[nn + 1] + (int)(pref >> 16);
    }
    __syncthreads();
    for (int e = e0 + t; e < e1; e += 256) {
        int c = col[e] - n0;
        if ((unsigned)c < (unsigned)nCnt) {
            int pos = atomicAdd(&base[c], 1);
            srcSorted[pos] = row[e];
        }
    }
}

// ---------- fused conv1: gather(d=64) -> LDS split-bf16 -> MFMA -> h1b ----------
__global__ __launch_bounds__(256) void k_conv1(const unsigned short* __restrict__ s,
                                               const int* __restrict__ offs,
                                               const int* __restrict__ srcs,
                                               const float* __restrict__ dis,
                                               const unsigned short* __restrict__ Bhi,
                                               const unsigned short* __restrict__ Blo,
                                               const float* __restrict__ b1,
                                               unsigned short* __restrict__ h1b, int N) {
    __shared__ unsigned short Ahi[16][72];
    __shared__ unsigned short Alo[16][72];
    int t = threadIdx.x;
    int lane = t & 63, wave = t >> 6;
    int quad = lane >> 4;
    short8 bh[2][2], bl[2][2];
#pragma unroll
    for (int ks = 0; ks < 2; ks++)
#pragma unroll
        for (int nt = 0; nt < 2; nt++) {
            int nb = wave * 2 + nt;
            bh[ks][nt] = *(const short8*)(Bhi + ((ks * 8 + nb) * 64 + lane) * 8);
            bl[ks][nt] = *(const short8*)(Blo + ((ks * 8 + nb) * 64 + lane) * 8);
        }
    {
        int nl = t >> 4;
        int node = blockIdx.x * 16 + nl;
        if (node < N) {
            int c4 = (t & 15) * 4;
            int e = offs[node], eEnd = offs[node + 1];
            float dn = dis[node];
            uint2 w = *(const uint2*)(s + (size_t)node * 64 + c4);
            float4 acc;
            acc.x = bf2f(w.x & 0xFFFF) * dn; acc.y = bf2f(w.x >> 16) * dn;
            acc.z = bf2f(w.y & 0xFFFF) * dn; acc.w = bf2f(w.y >> 16) * dn;
            // 4-edge unroll: 4 feature + 4 dis + 4 srcs loads in flight.
            // FP order identical to two iterations of the 2-edge loop.
            while (e + 3 < eEnd) {
                int sA = srcs[e], sB = srcs[e + 1], sC = srcs[e + 2], sD = srcs[e + 3];
                float dA = dis[sA], dB = dis[sB], dC = dis[sC], dD = dis[sD];
                uint2 vA = *(const uint2*)(s + (size_t)sA * 64 + c4);
                uint2 vB = *(const uint2*)(s + (size_t)sB * 64 + c4);
                uint2 vC = *(const uint2*)(s + (size_t)sC * 64 + c4);
                uint2 vD = *(const uint2*)(s + (size_t)sD * 64 + c4);
                acc.x += bf2f(vA.x & 0xFFFF) * dA + bf2f(vB.x & 0xFFFF) * dB;
                acc.y += bf2f(vA.x >> 16) * dA + bf2f(vB.x >> 16) * dB;
                acc.z += bf2f(vA.y & 0xFFFF) * dA + bf2f(vB.y & 0xFFFF) * dB;
                acc.w += bf2f(vA.y >> 16) * dA + bf2f(vB.y >> 16) * dB;
                acc.x += bf2f(vC.x & 0xFFFF) * dC + bf2f(vD.x & 0xFFFF) * dD;
                acc.y += bf2f(vC.x >> 16) * dC + bf2f(vD.x >> 16) * dD;
                acc.z += bf2f(vC.y & 0xFFFF) * dC + bf2f(vD.y & 0xFFFF) * dD;
                acc.w += bf2f(vC.y >> 16) * dC + bf2f(vD.y >> 16) * dD;
                e += 4;
            }
            while (e + 1 < eEnd) {
                int sA = srcs[e], sB = srcs[e + 1];
                float dA = dis[sA], dB = dis[sB];
                uint2 vA = *(const uint2*)(s + (size_t)sA * 64 + c4);
                uint2 vB = *(const uint2*)(s + (size_t)sB * 64 + c4);
                acc.x += bf2f(vA.x & 0xFFFF) * dA + bf2f(vB.x & 0xFFFF) * dB;
                acc.y += bf2f(vA.x >> 16) * dA + bf2f(vB.x >> 16) * dB;
                acc.z += bf2f(vA.y & 0xFFFF) * dA + bf2f(vB.y & 0xFFFF) * dB;
                acc.w += bf2f(vA.y >> 16) * dA + bf2f(vB.y >> 16) * dB;
                e += 2;
            }
            if (e < eEnd) {
                int sA = srcs[e];
                float dA = dis[sA];
                uint2 vA = *(const uint2*)(s + (size_t)sA * 64 + c4);
                acc.x += bf2f(vA.x & 0xFFFF) * dA; acc.y += bf2f(vA.x >> 16) * dA;
                acc.z += bf2f(vA.y & 0xFFFF) * dA; acc.w += bf2f(vA.y >> 16) * dA;
            }
            acc.x *= dn; acc.y *= dn; acc.z *= dn; acc.w *= dn;
            unsigned int h0 = f2bf(acc.x), h1 = f2bf(acc.y),
                         h2 = f2bf(acc.z), h3 = f2bf(acc.w);
            uint2 hw; hw.x = h0 | (h1 << 16); hw.y = h2 | (h3 << 16);
            uint2 lw;
            lw.x = f2bf(acc.x - bf2f(h0)) | (f2bf(acc.y - bf2f(h1)) << 16);
            lw.y = f2bf(acc.z - bf2f(h2)) | (f2bf(acc.w - bf2f(h3)) << 16);
            *(uint2*)(&Ahi[nl][c4]) = hw;
            *(uint2*)(&Alo[nl][c4]) = lw;
        }
    }
    __syncthreads();
    int ml = lane & 15;
    floatx4 acc[2] = {};
#pragma unroll
    for (int ks = 0; ks < 2; ks++) {
        short8 ahi = *(const short8*)(&Ahi[ml][ks * 32 + quad * 8]);
        short8 alo = *(const short8*)(&Alo[ml][ks * 32 + quad * 8]);
#pragma unroll
        for (int nt = 0; nt < 2; nt++) {
            acc[nt] = __builtin_amdgcn_mfma_f32_16x16x32_bf16(ahi, bh[ks][nt], acc[nt], 0, 0, 0);
            acc[nt] = __builtin_amdgcn_mfma_f32_16x16x32_bf16(ahi, bl[ks][nt], acc[nt], 0, 0, 0);
            acc[nt] = __builtin_amdgcn_mfma_f32_16x16x32_bf16(alo, bh[ks][nt], acc[nt], 0, 0, 0);
        }
    }
    int md = blockIdx.x * 16 + quad * 4;
#pragma unroll
    for (int nt = 0; nt < 2; nt++) {
        int n0 = (wave * 2 + nt) * 16 + (lane & 15);
        float bias = b1[n0];
#pragma unroll
        for (int r = 0; r < 4; r++) {
            int node = md + r;
            if (node < N)
                h1b[(size_t)node * 128 + n0] =
                    (unsigned short)f2bf(fmaxf(acc[nt][r] + bias, 0.f) * dis[node]);
        }
    }
}

// ---------- fused conv2: gather(d=128) -> LDS -> MFMA UV -> Ub|Vb ----------
// 16 nodes/block, 512 threads. Each node: 2x16-lane half-groups, each summing
// alternate edges (stride 2), combined via shfl_xor(.,16). Halves per-thread
// serial chain (16->8 edges) and doubles independent load chains.
__global__ __launch_bounds__(512) void k_conv2(const unsigned short* __restrict__ s,
                                               const int* __restrict__ offs,
                                               const int* __restrict__ srcs,
                                               const float* __restrict__ dis,
                                               const unsigned short* __restrict__ Bhi,
                                               const unsigned short* __restrict__ Blo,
                                               const float* __restrict__ buv,
                                               unsigned short* __restrict__ Ub,
                                               unsigned short* __restrict__ Vb, int N) {
    __shared__ unsigned short Ab[16][136];  // stride 68 words (same bank pattern as conv1's 72)
    int t = threadIdx.x;
    int lane = t & 63, wave = t >> 6;
    {
        int nl = wave * 2 + (lane >> 5);     // 0..15 node rows
        int node = blockIdx.x * 16 + nl;
        int half = (lane >> 4) & 1;
        int c8 = (lane & 15) * 8;
        float a0 = 0.f, a1 = 0.f, a2 = 0.f, a3 = 0.f,
              a4 = 0.f, a5 = 0.f, a6 = 0.f, a7 = 0.f;
        float dn = 0.f;
        if (node < N) {
            int eb = offs[node], eEnd = offs[node + 1];
            dn = dis[node];
            if (!half) {  // half 0 seeds with the self row; half 1 starts at 0
                uint4 w = *(const uint4*)(s + (size_t)node * 128 + c8);
                a0 = bf2f(w.x & 0xFFFF); a1 = bf2f(w.x >> 16);
                a2 = bf2f(w.y & 0xFFFF); a3 = bf2f(w.y >> 16);
                a4 = bf2f(w.z & 0xFFFF); a5 = bf2f(w.z >> 16);
                a6 = bf2f(w.w & 0xFFFF); a7 = bf2f(w.w >> 16);
            }
            int e = eb + half;               // this half's parity
            // 4-deep (stride-2) unroll: 4x16B feature loads in flight per half.
            while (e + 6 < eEnd) {
                int s0 = srcs[e], s1 = srcs[e + 2], s2 = srcs[e + 4], s3 = srcs[e + 6];
                uint4 v0 = *(const uint4*)(s + (size_t)s0 * 128 + c8);
                uint4 v1 = *(const uint4*)(s + (size_t)s1 * 128 + c8);
                uint4 v2 = *(const uint4*)(s + (size_t)s2 * 128 + c8);
                uint4 v3 = *(const uint4*)(s + (size_t)s3 * 128 + c8);
                a0 += bf2f(v0.x & 0xFFFF) + bf2f(v1.x & 0xFFFF);
                a1 += bf2f(v0.x >> 16) + bf2f(v1.x >> 16);
                a2 += bf2f(v0.y & 0xFFFF) + bf2f(v1.y & 0xFFFF);
                a3 += bf2f(v0.y >> 16) + bf2f(v1.y >> 16);
                a4 += bf2f(v0.z & 0xFFFF) + bf2f(v1.z & 0xFFFF);
                a5 += bf2f(v0.z >> 16) + bf2f(v1.z >> 16);
                a6 += bf2f(v0.w & 0xFFFF) + bf2f(v1.w & 0xFFFF);
                a7 += bf2f(v0.w >> 16) + bf2f(v1.w >> 16);
                a0 += bf2f(v2.x & 0xFFFF) + bf2f(v3.x & 0xFFFF);
                a1 += bf2f(v2.x >> 16) + bf2f(v3.x >> 16);
                a2 += bf2f(v2.y & 0xFFFF) + bf2f(v3.y & 0xFFFF);
                a3 += bf2f(v2.y >> 16) + bf2f(v3.y >> 16);
                a4 += bf2f(v2.z & 0xFFFF) + bf2f(v3.z & 0xFFFF);
                a5 += bf2f(v2.z >> 16) + bf2f(v3.z >> 16);
                a6 += bf2f(v2.w & 0xFFFF) + bf2f(v3.w & 0xFFFF);
                a7 += bf2f(v2.w >> 16) + bf2f(v3.w >> 16);
                e += 8;
            }
            while (e < eEnd) {
                int s0 = srcs[e];
                uint4 v0 = *(const uint4*)(s + (size_t)s0 * 128 + c8);
                a0 += bf2f(v0.x & 0xFFFF); a1 += bf2f(v0.x >> 16);
                a2 += bf2f(v0.y & 0xFFFF); a3 += bf2f(v0.y >> 16);
                a4 += bf2f(v0.z & 0xFFFF); a5 += bf2f(v0.z >> 16);
                a6 += bf2f(v0.w & 0xFFFF); a7 += bf2f(v0.w >> 16);
                e += 2;
            }
        }
        // combine the two half-group partials (lane ^ 16 within the wave)
        a0 += __shfl_xor(a0, 16); a1 += __shfl_xor(a1, 16);
        a2 += __shfl_xor(a2, 16); a3 += __shfl_xor(a3, 16);
        a4 += __shfl_xor(a4, 16); a5 += __shfl_xor(a5, 16);
        a6 += __shfl_xor(a6, 16); a7 += __shfl_xor(a7, 16);
        if (!half) {  // dn==0 when node>=N -> writes zeros
            uint4 o;
            o.x = f2bf(a0 * dn) | (f2bf(a1 * dn) << 16);
            o.y = f2bf(a2 * dn) | (f2bf(a3 * dn) << 16);
            o.z = f2bf(a4 * dn) | (f2bf(a5 * dn) << 16);
            o.w = f2bf(a6 * dn) | (f2bf(a7 * dn) << 16);
            *(uint4*)(&Ab[nl][c8]) = o;
        }
    }
    int quad = lane >> 4, ml = lane & 15;
    short8 bh[4][2], bl[4][2];
#pragma unroll
    for (int ks = 0; ks < 4; ks++)
#pragma unroll
        for (int nt = 0; nt < 2; nt++) {
            int nb = wave * 2 + nt;            // 0..15 col-tiles across 8 waves
            bh[ks][nt] = *(const short8*)(Bhi + ((ks * 16 + nb) * 64 + lane) * 8);
            bl[ks][nt] = *(const short8*)(Blo + ((ks * 16 + nb) * 64 + lane) * 8);
        }
    __syncthreads();
    floatx4 acc[2] = {};
#pragma unroll
    for (int ks = 0; ks < 4; ks++) {
        short8 a = *(const short8*)(&Ab[ml][ks * 32 + quad * 8]);
#pragma unroll
        for (int nt = 0; nt < 2; nt++) {
            acc[nt] = __builtin_amdgcn_mfma_f32_16x16x32_bf16(a, bh[ks][nt], acc[nt], 0, 0, 0);
            acc[nt] = __builtin_amdgcn_mfma_f32_16x16x32_bf16(a, bl[ks][nt], acc[nt], 0, 0, 0);
        }
    }
    int md = blockIdx.x * 16 + quad * 4;
#pragma unroll
    for (int nt = 0; nt < 2; nt++) {
        int n0 = (wave * 2 + nt) * 16 + ml;
        float bias = buv[n0];
        unsigned short* dst = (n0 < 128) ? Ub : Vb;
        int cc = n0 & 127;
#pragma unroll
        for (int r = 0; r < 4; r++) {
            int nd = md + r;
            if (nd < N)
                dst[(size_t)nd * 128 + cc] =
                    (unsigned short)f2bf(acc[nt][r] + bias);
        }
    }
}

// ---------- head: out[q] = relu(Ub[src]+Vb[dst]) . Wc2 + bc2 ----------
__global__ __launch_bounds__(256) void k_head(const unsigned short* __restrict__ Ub,
                                              const unsigned short* __restrict__ Vb,
                                              const int* __restrict__ srcA,
                                              const int* __restrict__ dstA,
                                              const float* __restrict__ Wc2,
                                              const float* __restrict__ bc2,
                                              float* __restrict__ out, int Q) {
    int t = threadIdx.x;
    int q = blockIdx.x * 16 + (t >> 4);
    if (q >= Q) return;
    int l = t & 15;
    int s = srcA[q], d = dstA[q];
    uint4 u = *(const uint4*)(Ub + (size_t)s * 128 + l * 8);
    uint4 v = *(const uint4*)(Vb + (size_t)d * 128 + l * 8);
    const float4* w = (const float4*)(Wc2 + l * 8);
    float4 w0 = w[0], w1 = w[1];
    float acc = 0.f, z;
    z = fmaxf(bf2f(u.x & 0xFFFF) + bf2f(v.x & 0xFFFF), 0.f); acc += z * w0.x;
    z = fmaxf(bf2f(u.x >> 16)    + bf2f(v.x >> 16),    0.f); acc += z * w0.y;
    z = fmaxf(bf2f(u.y & 0xFFFF) + bf2f(v.y & 0xFFFF), 0.f); acc += z * w0.z;
    z = fmaxf(bf2f(u.y >> 16)    + bf2f(v.y >> 16),    0.f); acc += z * w0.w;
    z = fmaxf(bf2f(u.z & 0xFFFF) + bf2f(v.z & 0xFFFF), 0.f); acc += z * w1.x;
    z = fmaxf(bf2f(u.z >> 16)    + bf2f(v.z >> 16),    0.f); acc += z * w1.y;
    z = fmaxf(bf2f(u.w & 0xFFFF) + bf2f(v.w & 0xFFFF), 0.f); acc += z * w1.z;
    z = fmaxf(bf2f(u.w >> 16)    + bf2f(v.w >> 16),    0.f); acc += z * w1.w;
    acc += __shfl_xor(acc, 1);
    acc += __shfl_xor(acc, 2);
    acc += __shfl_xor(acc, 4);
    acc += __shfl_xor(acc, 8);
    if (l == 0) out[q] = acc + bc2[0];
}

extern "C" void kernel_launch(void* const* d_in, const int* in_sizes, int n_in,
                              void* d_out, int out_size, void* d_ws, size_t ws_size,
                              hipStream_t stream) {
    const float* x   = (const float*)d_in[0];
    const int*   ei  = (const int*)d_in[1];
    const int*   eli = (const int*)d_in[2];
    const float* W1  = (const float*)d_in[3];
    const float* b1  = (const float*)d_in[4];
    const float* W2  = (const float*)d_in[5];
    const float* b2  = (const float*)d_in[6];
    const float* Wc1 = (const float*)d_in[7];
    const float* bc1 = (const float*)d_in[8];
    const float* Wc2 = (const float*)d_in[9];
    const float* bc2 = (const float*)d_in[10];
    float* out = (float*)d_out;
    char* wsb = (char*)d_ws;

    const int N = in_sizes[0] / 64;
    const int E = in_sizes[1] / 2;
    const int Q = in_sizes[2] / 2;
    const int W = (N + 1) / 2;
    const int chunk = (E + HB - 1) / HB;
    const int nPass = (N + NWIN - 1) / NWIN;   // fill windows (nodes)
    const int nWinH = (W + NWIN - 1) / NWIN;   // hist windows (words)
    const int nHist = HB * 2 * nWinH;
    const int nXb   = (N * 32 + 255) / 256;
    const int rsB   = (W + 255) / 256;         // k_rs blocks (512 nodes each)

    // workspace layout (word offsets, 4B units)
    float* dis       = (float*)wsb;                                // 65536
    int*   offs      = (int*)wsb + 65536;                          // N+1
    int*   bsum      = (int*)wsb + 197120;                         // 256
    float* buv       = (float*)wsb + 262912;                       // 256
    unsigned short* UVhi = (unsigned short*)((int*)wsb + 263168);  // 32768 us
    unsigned short* UVlo = (unsigned short*)((int*)wsb + 279552);
    unsigned short* W1hi = (unsigned short*)((int*)wsb + 295936);  // 8192 us
    unsigned short* W1lo = (unsigned short*)((int*)wsb + 300032);
    int*   srcSorted = (int*)wsb + 304128;                         // E -> 1104128
    unsigned short* Vb   = (unsigned short*)((int*)wsb + 1104128); // N*128 us -> 4304128
    unsigned short* h1b  = (unsigned short*)((int*)wsb + 4304128); // N*128 us -> 7504128
    unsigned short* Ub   = (unsigned short*)((int*)wsb + 7504128); // N*128 us (h1b still live in k_conv2!)
    unsigned int* hRow = (unsigned int*)wsb + 10704128;            // HB*W -> 12304128
    unsigned int* hCol = (unsigned int*)wsb + 12304128;            // HB*W -> 13904128
    unsigned int* xb   = (unsigned int*)wsb + 13904128;            // N*32 words -> 15504128

    const int* row  = ei;
    const int* col  = ei + E;
    const int* srcA = eli;
    const int* dstA = eli + Q;

    k_pre<<<nHist + nXb + 161, 256, 0, stream>>>(
        row, col, hRow, hCol, x, xb, W1, W2, Wc1, b2, bc1,
        UVhi, UVlo, W1hi, W1lo, buv, E, N, W, chunk, nHist, nXb);
    k_rs<<<rsB, 256, 0, stream>>>(hRow, hCol, dis, offs, bsum, N, W);
    k_scan2<<<1, 256, 0, stream>>>(bsum, rsB);
    k_scan3<<<(N + 255) / 256, 256, 0, stream>>>(offs, bsum, N, E);
    k_fill3<<<dim3(HB, nPass), 256, 0, stream>>>(row, col, offs, hCol, srcSorted, E, N, W, chunk);
    k_conv1<<<(N + 15) / 16, 256, 0, stream>>>(
        (const unsigned short*)xb, offs, srcSorted, dis, W1hi, W1lo, b1, h1b, N);
    k_conv2<<<(N + 15) / 16, 512, 0, stream>>>(
        h1b, offs, srcSorted, dis, UVhi, UVlo, buv, Ub, Vb, N);
    k_head<<<(Q + 15) / 16, 256, 0, stream>>>(Ub, Vb, srcA, dstA, Wc2, bc2, out, Q);
}

// Round 6
// 248.308 us; speedup vs baseline: 1.0522x; 1.0522x over previous
//
#include <hip/hip_runtime.h>

// N=50000, E=800000, Q=200000, d_in=64, h=128
// bf16 random-access features; split-bf16 MFMA; atomic-free CSR build (HB=64);
// fusions: hist+xb+fold (k_pre); reduce+scan1 (k_rs); gather1+mfma1 (k_conv1);
//          gather2+mfmaUV (k_conv2). Best-of recombination: conv1 4-edge
//          (8-edge regressed it), conv2 8-edge 32-nodes/block (48.2us best;
//          half-group split regressed to 59.6 -- B-reload + tail imbalance).

#define HB 64       // histogram / fill chunks
#define NWIN 16384  // node/word window (64KB LDS)

typedef __attribute__((ext_vector_type(8))) short short8;
typedef __attribute__((ext_vector_type(4))) float floatx4;

static __device__ __forceinline__ unsigned int f2bf(float v) {
    union { float f; unsigned int u; } c; c.f = v;
    unsigned int lsb = (c.u >> 16) & 1u;
    c.u += 0x7FFFu + lsb;                 // round-to-nearest-even
    return c.u >> 16;
}
static __device__ __forceinline__ float bf2f(unsigned int h) {
    union { float f; unsigned int u; } c; c.u = h << 16;
    return c.f;
}

// ---------- fused prologue: histogram + x->bf16 + weight fold/pack ----------
__global__ __launch_bounds__(256) void k_pre(const int* __restrict__ row,
                                             const int* __restrict__ col,
                                             unsigned int* __restrict__ hRow,
                                             unsigned int* __restrict__ hCol,
                                             const float* __restrict__ x,
                                             unsigned int* __restrict__ xb,
                                             const float* __restrict__ W1,
                                             const float* __restrict__ W2,
                                             const float* __restrict__ Wc1,
                                             const float* __restrict__ b2,
                                             const float* __restrict__ bc1,
                                             unsigned short* __restrict__ UVhi,
                                             unsigned short* __restrict__ UVlo,
                                             unsigned short* __restrict__ W1hi,
                                             unsigned short* __restrict__ W1lo,
                                             float* __restrict__ buv,
                                             int E, int N, int W, int chunk,
                                             int nHist, int nXb) {
    __shared__ unsigned int lds[NWIN];
    int t = threadIdx.x, b = blockIdx.x;
    if (b < nHist) {
        int hb = b % HB;
        int yb = b / HB;
        int p = yb >> 1, win = yb & 1;
        int base = win * NWIN;
        int wcap = min(W - base, NWIN);
        if (wcap <= 0) return;
        const int* idxArr = p ? col : row;
        unsigned int* outArr = p ? hCol : hRow;
        int e0 = hb * chunk, e1 = min(E, e0 + chunk);
        for (int i = t; i < wcap; i += 256) lds[i] = 0;
        __syncthreads();
        for (int e = e0 + t; e < e1; e += 256) {
            int idx = idxArr[e];
            int w = (idx >> 1) - base;
            if ((unsigned)w < (unsigned)wcap)
                atomicAdd(&lds[w], 1u << ((idx & 1) * 16));
        }
        __syncthreads();
        for (int i = t; i < wcap; i += 256)
            outArr[(size_t)hb * W + base + i] = lds[i];
    } else if (b < nHist + nXb) {
        int i = (b - nHist) * 256 + t;
        if (i < N * 32) {
            float2 v = ((const float2*)x)[i];
            xb[i] = f2bf(v.x) | (f2bf(v.y) << 16);
        }
    } else {
        int bf = b - nHist - nXb;
        float* w2row = (float*)lds;
        if (bf < 128) {
            int k = bf;
            int j = t & 127, half = t >> 7;
            int n = half * 128 + j;
            const float* wc = Wc1 + (size_t)half * 128 * 128 + j;
            if (t < 128) w2row[t] = W2[k * 128 + t];
            __syncthreads();
            float acc = 0.f;
#pragma unroll 8
            for (int m = 0; m < 128; m++) acc += w2row[m] * wc[(size_t)m * 128];
            int kstep = k >> 5, kl = k & 31, quad = kl >> 3, j8 = kl & 7;
            int nb = n >> 4, l = quad * 16 + (n & 15);
            int pidx = ((kstep * 16 + nb) * 64 + l) * 8 + j8;
            unsigned int h = f2bf(acc);
            UVhi[pidx] = (unsigned short)h;
            UVlo[pidx] = (unsigned short)f2bf(acc - bf2f(h));
        } else if (bf == 128) {
            int j = t & 127, half = t >> 7;
            const float* wc = Wc1 + (size_t)half * 128 * 128 + j;
            float acc = half ? 0.f : bc1[j];
#pragma unroll 8
            for (int m = 0; m < 128; m++) acc += b2[m] * wc[(size_t)m * 128];
            buv[half * 128 + j] = acc;
        } else {
            int idx = (bf - 129) * 256 + t;  // < 8192
            int k = idx >> 7, n = idx & 127;
            float v = W1[k * 128 + n];
            int kstep = k >> 5, kl = k & 31, quad = kl >> 3, j8 = kl & 7;
            int nb = n >> 4, l = quad * 16 + (n & 15);
            int pidx = ((kstep * 8 + nb) * 64 + l) * 8 + j8;
            unsigned int h = f2bf(v);
            W1hi[pidx] = (unsigned short)h;
            W1lo[pidx] = (unsigned short)f2bf(v - bf2f(h));
        }
    }
}

// ---------- fused reduce + block-local scan ----------
__global__ __launch_bounds__(256) void k_rs(const unsigned int* __restrict__ hRow,
                                            unsigned int* __restrict__ hCol,
                                            float* __restrict__ dis,
                                            int* __restrict__ offs,
                                            int* __restrict__ bsum,
                                            int N, int W) {
    __shared__ int ts[256];
    int t = threadIdx.x;
    int w = blockIdx.x * 256 + t;
    unsigned int r0 = 0, r1 = 0, c0 = 0, c1 = 0;
    if (w < W) {
#pragma unroll 8
        for (int b = 0; b < HB; b++) {
            size_t idx = (size_t)b * W + w;
            unsigned int hr = hRow[idx];
            unsigned int hc = hCol[idx];
            hCol[idx] = c0 | (c1 << 16);   // exclusive prefix over blocks
            r0 += hr & 0xFFFFu; r1 += hr >> 16;
            c0 += hc & 0xFFFFu; c1 += hc >> 16;
        }
        int n0 = 2 * w, n1 = 2 * w + 1;
        dis[n0] = 1.0f / sqrtf((float)(r0 + 1));
        if (n1 < N) dis[n1] = 1.0f / sqrtf((float)(r1 + 1));
    }
    int sum = (w < W) ? (int)(c0 + c1) : 0;
    ts[t] = sum;
    __syncthreads();
    for (int off = 1; off < 256; off <<= 1) {
        int xv = (t >= off) ? ts[t - off] : 0;
        __syncthreads();
        ts[t] += xv;
        __syncthreads();
    }
    int e = ts[t] - sum;  // exclusive within block
    if (w < W) {
        int n0 = 2 * w, n1 = 2 * w + 1;
        offs[n0] = e;
        if (n1 < N) offs[n1] = e + (int)c0;
    }
    if (t == 255) bsum[blockIdx.x] = ts[255];
}

__global__ __launch_bounds__(256) void k_scan2(int* __restrict__ bsum, int B) {
    __shared__ int ts[256];
    int t = threadIdx.x;
    int v = (t < B) ? bsum[t] : 0;
    ts[t] = v;
    __syncthreads();
    for (int off = 1; off < 256; off <<= 1) {
        int x = (t >= off) ? ts[t - off] : 0;
        __syncthreads();
        ts[t] += x;
        __syncthreads();
    }
    if (t < B) bsum[t] = ts[t] - v;
}

// each k_rs block covered 512 nodes -> bsum index = i >> 9
__global__ __launch_bounds__(256) void k_scan3(int* __restrict__ offs,
                                               const int* __restrict__ bsum,
                                               int N, int E) {
    int i = blockIdx.x * 256 + threadIdx.x;
    if (i < N) offs[i] = offs[i] + bsum[i >> 9];
    if (i == 0) offs[N] = E;
}

// ---------- CSR fill, atomic-free, 2D grid ----------
__global__ __launch_bounds__(256) void k_fill3(const int* __restrict__ row,
                                               const int* __restrict__ col,
                                               const int* __restrict__ offs,
                                               const unsigned int* __restrict__ hCol,
                                               int* __restrict__ srcSorted,
                                               int E, int N, int W, int chunk) {
    __shared__ int base[NWIN];
    int t = threadIdx.x, b = blockIdx.x;
    int n0 = blockIdx.y * NWIN;
    int nCnt = min(NWIN, N - n0);
    int e0 = b * chunk, e1 = min(E, e0 + chunk);
    for (int wl = t; wl * 2 < nCnt; wl += 256) {
        unsigned int pref = hCol[(size_t)b * W + (n0 >> 1) + wl];
        int nn = n0 + wl * 2;
        base[wl * 2] = offs[nn] + (int)(pref & 0xFFFFu);
        if (wl * 2 + 1 < nCnt)
            base[wl * 2 + 1] = offs[nn + 1] + (int)(pref >> 16);
    }
    __syncthreads();
    for (int e = e0 + t; e < e1; e += 256) {
        int c = col[e] - n0;
        if ((unsigned)c < (unsigned)nCnt) {
            int pos = atomicAdd(&base[c], 1);
            srcSorted[pos] = row[e];
        }
    }
}

// ---------- fused conv1: gather(d=64) -> LDS split-bf16 -> MFMA -> h1b ----------
__global__ __launch_bounds__(256) void k_conv1(const unsigned short* __restrict__ s,
                                               const int* __restrict__ offs,
                                               const int* __restrict__ srcs,
                                               const float* __restrict__ dis,
                                               const unsigned short* __restrict__ Bhi,
                                               const unsigned short* __restrict__ Blo,
                                               const float* __restrict__ b1,
                                               unsigned short* __restrict__ h1b, int N) {
    __shared__ unsigned short Ahi[16][72];
    __shared__ unsigned short Alo[16][72];
    int t = threadIdx.x;
    int lane = t & 63, wave = t >> 6;
    int quad = lane >> 4;
    short8 bh[2][2], bl[2][2];
#pragma unroll
    for (int ks = 0; ks < 2; ks++)
#pragma unroll
        for (int nt = 0; nt < 2; nt++) {
            int nb = wave * 2 + nt;
            bh[ks][nt] = *(const short8*)(Bhi + ((ks * 8 + nb) * 64 + lane) * 8);
            bl[ks][nt] = *(const short8*)(Blo + ((ks * 8 + nb) * 64 + lane) * 8);
        }
    {
        int nl = t >> 4;
        int node = blockIdx.x * 16 + nl;
        if (node < N) {
            int c4 = (t & 15) * 4;
            int e = offs[node], eEnd = offs[node + 1];
            float dn = dis[node];
            uint2 w = *(const uint2*)(s + (size_t)node * 64 + c4);
            float4 acc;
            acc.x = bf2f(w.x & 0xFFFF) * dn; acc.y = bf2f(w.x >> 16) * dn;
            acc.z = bf2f(w.y & 0xFFFF) * dn; acc.w = bf2f(w.y >> 16) * dn;
            // 4-edge unroll: 4 feature + 4 dis + 4 srcs loads in flight.
            // FP order identical to two iterations of the 2-edge loop.
            while (e + 3 < eEnd) {
                int sA = srcs[e], sB = srcs[e + 1], sC = srcs[e + 2], sD = srcs[e + 3];
                float dA = dis[sA], dB = dis[sB], dC = dis[sC], dD = dis[sD];
                uint2 vA = *(const uint2*)(s + (size_t)sA * 64 + c4);
                uint2 vB = *(const uint2*)(s + (size_t)sB * 64 + c4);
                uint2 vC = *(const uint2*)(s + (size_t)sC * 64 + c4);
                uint2 vD = *(const uint2*)(s + (size_t)sD * 64 + c4);
                acc.x += bf2f(vA.x & 0xFFFF) * dA + bf2f(vB.x & 0xFFFF) * dB;
                acc.y += bf2f(vA.x >> 16) * dA + bf2f(vB.x >> 16) * dB;
                acc.z += bf2f(vA.y & 0xFFFF) * dA + bf2f(vB.y & 0xFFFF) * dB;
                acc.w += bf2f(vA.y >> 16) * dA + bf2f(vB.y >> 16) * dB;
                acc.x += bf2f(vC.x & 0xFFFF) * dC + bf2f(vD.x & 0xFFFF) * dD;
                acc.y += bf2f(vC.x >> 16) * dC + bf2f(vD.x >> 16) * dD;
                acc.z += bf2f(vC.y & 0xFFFF) * dC + bf2f(vD.y & 0xFFFF) * dD;
                acc.w += bf2f(vC.y >> 16) * dC + bf2f(vD.y >> 16) * dD;
                e += 4;
            }
            while (e + 1 < eEnd) {
                int sA = srcs[e], sB = srcs[e + 1];
                float dA = dis[sA], dB = dis[sB];
                uint2 vA = *(const uint2*)(s + (size_t)sA * 64 + c4);
                uint2 vB = *(const uint2*)(s + (size_t)sB * 64 + c4);
                acc.x += bf2f(vA.x & 0xFFFF) * dA + bf2f(vB.x & 0xFFFF) * dB;
                acc.y += bf2f(vA.x >> 16) * dA + bf2f(vB.x >> 16) * dB;
                acc.z += bf2f(vA.y & 0xFFFF) * dA + bf2f(vB.y & 0xFFFF) * dB;
                acc.w += bf2f(vA.y >> 16) * dA + bf2f(vB.y >> 16) * dB;
                e += 2;
            }
            if (e < eEnd) {
                int sA = srcs[e];
                float dA = dis[sA];
                uint2 vA = *(const uint2*)(s + (size_t)sA * 64 + c4);
                acc.x += bf2f(vA.x & 0xFFFF) * dA; acc.y += bf2f(vA.x >> 16) * dA;
                acc.z += bf2f(vA.y & 0xFFFF) * dA; acc.w += bf2f(vA.y >> 16) * dA;
            }
            acc.x *= dn; acc.y *= dn; acc.z *= dn; acc.w *= dn;
            unsigned int h0 = f2bf(acc.x), h1 = f2bf(acc.y),
                         h2 = f2bf(acc.z), h3 = f2bf(acc.w);
            uint2 hw; hw.x = h0 | (h1 << 16); hw.y = h2 | (h3 << 16);
            uint2 lw;
            lw.x = f2bf(acc.x - bf2f(h0)) | (f2bf(acc.y - bf2f(h1)) << 16);
            lw.y = f2bf(acc.z - bf2f(h2)) | (f2bf(acc.w - bf2f(h3)) << 16);
            *(uint2*)(&Ahi[nl][c4]) = hw;
            *(uint2*)(&Alo[nl][c4]) = lw;
        }
    }
    __syncthreads();
    int ml = lane & 15;
    floatx4 acc[2] = {};
#pragma unroll
    for (int ks = 0; ks < 2; ks++) {
        short8 ahi = *(const short8*)(&Ahi[ml][ks * 32 + quad * 8]);
        short8 alo = *(const short8*)(&Alo[ml][ks * 32 + quad * 8]);
#pragma unroll
        for (int nt = 0; nt < 2; nt++) {
            acc[nt] = __builtin_amdgcn_mfma_f32_16x16x32_bf16(ahi, bh[ks][nt], acc[nt], 0, 0, 0);
            acc[nt] = __builtin_amdgcn_mfma_f32_16x16x32_bf16(ahi, bl[ks][nt], acc[nt], 0, 0, 0);
            acc[nt] = __builtin_amdgcn_mfma_f32_16x16x32_bf16(alo, bh[ks][nt], acc[nt], 0, 0, 0);
        }
    }
    int md = blockIdx.x * 16 + quad * 4;
#pragma unroll
    for (int nt = 0; nt < 2; nt++) {
        int n0 = (wave * 2 + nt) * 16 + (lane & 15);
        float bias = b1[n0];
#pragma unroll
        for (int r = 0; r < 4; r++) {
            int node = md + r;
            if (node < N)
                h1b[(size_t)node * 128 + n0] =
                    (unsigned short)f2bf(fmaxf(acc[nt][r] + bias, 0.f) * dis[node]);
        }
    }
}

// ---------- fused conv2: gather(d=128) -> LDS -> MFMA UV -> Ub|Vb ----------
// 32 nodes/block, 512 threads; gather 8-edge unrolled (measured best: 48.2us).
__global__ __launch_bounds__(512) void k_conv2(const unsigned short* __restrict__ s,
                                               const int* __restrict__ offs,
                                               const int* __restrict__ srcs,
                                               const float* __restrict__ dis,
                                               const unsigned short* __restrict__ Bhi,
                                               const unsigned short* __restrict__ Blo,
                                               const float* __restrict__ buv,
                                               unsigned short* __restrict__ Ub,
                                               unsigned short* __restrict__ Vb, int N) {
    __shared__ unsigned short Ab[32][136];  // stride 68 words -> worst 2-way bank alias (free)
    int t = threadIdx.x;
    {
        int nl = t >> 4;                     // 0..31
        int node = blockIdx.x * 32 + nl;
        int c8 = (t & 15) * 8;
        if (node < N) {
            int e = offs[node], eEnd = offs[node + 1];
            float dn = dis[node];
            uint4 w = *(const uint4*)(s + (size_t)node * 128 + c8);
            float a0 = bf2f(w.x & 0xFFFF), a1 = bf2f(w.x >> 16);
            float a2 = bf2f(w.y & 0xFFFF), a3 = bf2f(w.y >> 16);
            float a4 = bf2f(w.z & 0xFFFF), a5 = bf2f(w.z >> 16);
            float a6 = bf2f(w.w & 0xFFFF), a7 = bf2f(w.w >> 16);
            // 8-edge unroll: 8x16B feature loads in flight.
            // FP order identical to four iterations of the 2-edge loop.
            while (e + 7 < eEnd) {
                int s0 = srcs[e],     s1 = srcs[e + 1], s2 = srcs[e + 2], s3 = srcs[e + 3];
                int s4 = srcs[e + 4], s5 = srcs[e + 5], s6 = srcs[e + 6], s7 = srcs[e + 7];
                uint4 v0 = *(const uint4*)(s + (size_t)s0 * 128 + c8);
                uint4 v1 = *(const uint4*)(s + (size_t)s1 * 128 + c8);
                uint4 v2 = *(const uint4*)(s + (size_t)s2 * 128 + c8);
                uint4 v3 = *(const uint4*)(s + (size_t)s3 * 128 + c8);
                uint4 v4 = *(const uint4*)(s + (size_t)s4 * 128 + c8);
                uint4 v5 = *(const uint4*)(s + (size_t)s5 * 128 + c8);
                uint4 v6 = *(const uint4*)(s + (size_t)s6 * 128 + c8);
                uint4 v7 = *(const uint4*)(s + (size_t)s7 * 128 + c8);
                a0 += bf2f(v0.x & 0xFFFF) + bf2f(v1.x & 0xFFFF);
                a1 += bf2f(v0.x >> 16) + bf2f(v1.x >> 16);
                a2 += bf2f(v0.y & 0xFFFF) + bf2f(v1.y & 0xFFFF);
                a3 += bf2f(v0.y >> 16) + bf2f(v1.y >> 16);
                a4 += bf2f(v0.z & 0xFFFF) + bf2f(v1.z & 0xFFFF);
                a5 += bf2f(v0.z >> 16) + bf2f(v1.z >> 16);
                a6 += bf2f(v0.w & 0xFFFF) + bf2f(v1.w & 0xFFFF);
                a7 += bf2f(v0.w >> 16) + bf2f(v1.w >> 16);
                a0 += bf2f(v2.x & 0xFFFF) + bf2f(v3.x & 0xFFFF);
                a1 += bf2f(v2.x >> 16) + bf2f(v3.x >> 16);
                a2 += bf2f(v2.y & 0xFFFF) + bf2f(v3.y & 0xFFFF);
                a3 += bf2f(v2.y >> 16) + bf2f(v3.y >> 16);
                a4 += bf2f(v2.z & 0xFFFF) + bf2f(v3.z & 0xFFFF);
                a5 += bf2f(v2.z >> 16) + bf2f(v3.z >> 16);
                a6 += bf2f(v2.w & 0xFFFF) + bf2f(v3.w & 0xFFFF);
                a7 += bf2f(v2.w >> 16) + bf2f(v3.w >> 16);
                a0 += bf2f(v4.x & 0xFFFF) + bf2f(v5.x & 0xFFFF);
                a1 += bf2f(v4.x >> 16) + bf2f(v5.x >> 16);
                a2 += bf2f(v4.y & 0xFFFF) + bf2f(v5.y & 0xFFFF);
                a3 += bf2f(v4.y >> 16) + bf2f(v5.y >> 16);
                a4 += bf2f(v4.z & 0xFFFF) + bf2f(v5.z & 0xFFFF);
                a5 += bf2f(v4.z >> 16) + bf2f(v5.z >> 16);
                a6 += bf2f(v4.w & 0xFFFF) + bf2f(v5.w & 0xFFFF);
                a7 += bf2f(v4.w >> 16) + bf2f(v5.w >> 16);
                a0 += bf2f(v6.x & 0xFFFF) + bf2f(v7.x & 0xFFFF);
                a1 += bf2f(v6.x >> 16) + bf2f(v7.x >> 16);
                a2 += bf2f(v6.y & 0xFFFF) + bf2f(v7.y & 0xFFFF);
                a3 += bf2f(v6.y >> 16) + bf2f(v7.y >> 16);
                a4 += bf2f(v6.z & 0xFFFF) + bf2f(v7.z & 0xFFFF);
                a5 += bf2f(v6.z >> 16) + bf2f(v7.z >> 16);
                a6 += bf2f(v6.w & 0xFFFF) + bf2f(v7.w & 0xFFFF);
                a7 += bf2f(v6.w >> 16) + bf2f(v7.w >> 16);
                e += 8;
            }
            while (e + 3 < eEnd) {
                int sA = srcs[e], sB = srcs[e + 1], sC = srcs[e + 2], sD = srcs[e + 3];
                uint4 vA = *(const uint4*)(s + (size_t)sA * 128 + c8);
                uint4 vB = *(const uint4*)(s + (size_t)sB * 128 + c8);
                uint4 vC = *(const uint4*)(s + (size_t)sC * 128 + c8);
                uint4 vD = *(const uint4*)(s + (size_t)sD * 128 + c8);
                a0 += bf2f(vA.x & 0xFFFF) + bf2f(vB.x & 0xFFFF);
                a1 += bf2f(vA.x >> 16) + bf2f(vB.x >> 16);
                a2 += bf2f(vA.y & 0xFFFF) + bf2f(vB.y & 0xFFFF);
                a3 += bf2f(vA.y >> 16) + bf2f(vB.y >> 16);
                a4 += bf2f(vA.z & 0xFFFF) + bf2f(vB.z & 0xFFFF);
                a5 += bf2f(vA.z >> 16) + bf2f(vB.z >> 16);
                a6 += bf2f(vA.w & 0xFFFF) + bf2f(vB.w & 0xFFFF);
                a7 += bf2f(vA.w >> 16) + bf2f(vB.w >> 16);
                a0 += bf2f(vC.x & 0xFFFF) + bf2f(vD.x & 0xFFFF);
                a1 += bf2f(vC.x >> 16) + bf2f(vD.x >> 16);
                a2 += bf2f(vC.y & 0xFFFF) + bf2f(vD.y & 0xFFFF);
                a3 += bf2f(vC.y >> 16) + bf2f(vD.y >> 16);
                a4 += bf2f(vC.z & 0xFFFF) + bf2f(vD.z & 0xFFFF);
                a5 += bf2f(vC.z >> 16) + bf2f(vD.z >> 16);
                a6 += bf2f(vC.w & 0xFFFF) + bf2f(vD.w & 0xFFFF);
                a7 += bf2f(vC.w >> 16) + bf2f(vD.w >> 16);
                e += 4;
            }
            while (e + 1 < eEnd) {
                int sA = srcs[e], sB = srcs[e + 1];
                uint4 vA = *(const uint4*)(s + (size_t)sA * 128 + c8);
                uint4 vB = *(const uint4*)(s + (size_t)sB * 128 + c8);
                a0 += bf2f(vA.x & 0xFFFF) + bf2f(vB.x & 0xFFFF);
                a1 += bf2f(vA.x >> 16) + bf2f(vB.x >> 16);
                a2 += bf2f(vA.y & 0xFFFF) + bf2f(vB.y & 0xFFFF);
                a3 += bf2f(vA.y >> 16) + bf2f(vB.y >> 16);
                a4 += bf2f(vA.z & 0xFFFF) + bf2f(vB.z & 0xFFFF);
                a5 += bf2f(vA.z >> 16) + bf2f(vB.z >> 16);
                a6 += bf2f(vA.w & 0xFFFF) + bf2f(vB.w & 0xFFFF);
                a7 += bf2f(vA.w >> 16) + bf2f(vB.w >> 16);
                e += 2;
            }
            if (e < eEnd) {
                int sA = srcs[e];
                uint4 vA = *(const uint4*)(s + (size_t)sA * 128 + c8);
                a0 += bf2f(vA.x & 0xFFFF); a1 += bf2f(vA.x >> 16);
                a2 += bf2f(vA.y & 0xFFFF); a3 += bf2f(vA.y >> 16);
                a4 += bf2f(vA.z & 0xFFFF); a5 += bf2f(vA.z >> 16);
                a6 += bf2f(vA.w & 0xFFFF); a7 += bf2f(vA.w >> 16);
            }
            uint4 o;
            o.x = f2bf(a0 * dn) | (f2bf(a1 * dn) << 16);
            o.y = f2bf(a2 * dn) | (f2bf(a3 * dn) << 16);
            o.z = f2bf(a4 * dn) | (f2bf(a5 * dn) << 16);
            o.w = f2bf(a6 * dn) | (f2bf(a7 * dn) << 16);
            *(uint4*)(&Ab[nl][c8]) = o;
        } else {
            uint4 z; z.x = 0; z.y = 0; z.z = 0; z.w = 0;
            *(uint4*)(&Ab[nl][c8]) = z;
        }
    }
    int lane = t & 63, wave = t >> 6, quad = lane >> 4, ml = lane & 15;
    short8 bh[4][2], bl[4][2];
#pragma unroll
    for (int ks = 0; ks < 4; ks++)
#pragma unroll
        for (int nt = 0; nt < 2; nt++) {
            int nb = wave * 2 + nt;            // 0..15 col-tiles across 8 waves
            bh[ks][nt] = *(const short8*)(Bhi + ((ks * 16 + nb) * 64 + lane) * 8);
            bl[ks][nt] = *(const short8*)(Blo + ((ks * 16 + nb) * 64 + lane) * 8);
        }
    __syncthreads();
#pragma unroll
    for (int g = 0; g < 2; g++) {
        int mbase = blockIdx.x * 32 + g * 16;
        floatx4 acc[2] = {};
#pragma unroll
        for (int ks = 0; ks < 4; ks++) {
            short8 a = *(const short8*)(&Ab[g * 16 + ml][ks * 32 + quad * 8]);
#pragma unroll
            for (int nt = 0; nt < 2; nt++) {
                acc[nt] = __builtin_amdgcn_mfma_f32_16x16x32_bf16(a, bh[ks][nt], acc[nt], 0, 0, 0);
                acc[nt] = __builtin_amdgcn_mfma_f32_16x16x32_bf16(a, bl[ks][nt], acc[nt], 0, 0, 0);
            }
        }
        int md = mbase + quad * 4;
#pragma unroll
        for (int nt = 0; nt < 2; nt++) {
            int n0 = (wave * 2 + nt) * 16 + ml;
            float bias = buv[n0];
            unsigned short* dst = (n0 < 128) ? Ub : Vb;
            int cc = n0 & 127;
#pragma unroll
            for (int r = 0; r < 4; r++) {
                int nd = md + r;
                if (nd < N)
                    dst[(size_t)nd * 128 + cc] =
                        (unsigned short)f2bf(acc[nt][r] + bias);
            }
        }
    }
}

// ---------- head: out[q] = relu(Ub[src]+Vb[dst]) . Wc2 + bc2 ----------
__global__ __launch_bounds__(256) void k_head(const unsigned short* __restrict__ Ub,
                                              const unsigned short* __restrict__ Vb,
                                              const int* __restrict__ srcA,
                                              const int* __restrict__ dstA,
                                              const float* __restrict__ Wc2,
                                              const float* __restrict__ bc2,
                                              float* __restrict__ out, int Q) {
    int t = threadIdx.x;
    int q = blockIdx.x * 16 + (t >> 4);
    if (q >= Q) return;
    int l = t & 15;
    int s = srcA[q], d = dstA[q];
    uint4 u = *(const uint4*)(Ub + (size_t)s * 128 + l * 8);
    uint4 v = *(const uint4*)(Vb + (size_t)d * 128 + l * 8);
    const float4* w = (const float4*)(Wc2 + l * 8);
    float4 w0 = w[0], w1 = w[1];
    float acc = 0.f, z;
    z = fmaxf(bf2f(u.x & 0xFFFF) + bf2f(v.x & 0xFFFF), 0.f); acc += z * w0.x;
    z = fmaxf(bf2f(u.x >> 16)    + bf2f(v.x >> 16),    0.f); acc += z * w0.y;
    z = fmaxf(bf2f(u.y & 0xFFFF) + bf2f(v.y & 0xFFFF), 0.f); acc += z * w0.z;
    z = fmaxf(bf2f(u.y >> 16)    + bf2f(v.y >> 16),    0.f); acc += z * w0.w;
    z = fmaxf(bf2f(u.z & 0xFFFF) + bf2f(v.z & 0xFFFF), 0.f); acc += z * w1.x;
    z = fmaxf(bf2f(u.z >> 16)    + bf2f(v.z >> 16),    0.f); acc += z * w1.y;
    z = fmaxf(bf2f(u.w & 0xFFFF) + bf2f(v.w & 0xFFFF), 0.f); acc += z * w1.z;
    z = fmaxf(bf2f(u.w >> 16)    + bf2f(v.w >> 16),    0.f); acc += z * w1.w;
    acc += __shfl_xor(acc, 1);
    acc += __shfl_xor(acc, 2);
    acc += __shfl_xor(acc, 4);
    acc += __shfl_xor(acc, 8);
    if (l == 0) out[q] = acc + bc2[0];
}

extern "C" void kernel_launch(void* const* d_in, const int* in_sizes, int n_in,
                              void* d_out, int out_size, void* d_ws, size_t ws_size,
                              hipStream_t stream) {
    const float* x   = (const float*)d_in[0];
    const int*   ei  = (const int*)d_in[1];
    const int*   eli = (const int*)d_in[2];
    const float* W1  = (const float*)d_in[3];
    const float* b1  = (const float*)d_in[4];
    const float* W2  = (const float*)d_in[5];
    const float* b2  = (const float*)d_in[6];
    const float* Wc1 = (const float*)d_in[7];
    const float* bc1 = (const float*)d_in[8];
    const float* Wc2 = (const float*)d_in[9];
    const float* bc2 = (const float*)d_in[10];
    float* out = (float*)d_out;
    char* wsb = (char*)d_ws;

    const int N = in_sizes[0] / 64;
    const int E = in_sizes[1] / 2;
    const int Q = in_sizes[2] / 2;
    const int W = (N + 1) / 2;
    const int chunk = (E + HB - 1) / HB;
    const int nPass = (N + NWIN - 1) / NWIN;   // fill windows (nodes)
    const int nWinH = (W + NWIN - 1) / NWIN;   // hist windows (words)
    const int nHist = HB * 2 * nWinH;
    const int nXb   = (N * 32 + 255) / 256;
    const int rsB   = (W + 255) / 256;         // k_rs blocks (512 nodes each)

    // workspace layout (word offsets, 4B units)
    float* dis       = (float*)wsb;                                // 65536
    int*   offs      = (int*)wsb + 65536;                          // N+1
    int*   bsum      = (int*)wsb + 197120;                         // 256
    float* buv       = (float*)wsb + 262912;                       // 256
    unsigned short* UVhi = (unsigned short*)((int*)wsb + 263168);  // 32768 us
    unsigned short* UVlo = (unsigned short*)((int*)wsb + 279552);
    unsigned short* W1hi = (unsigned short*)((int*)wsb + 295936);  // 8192 us
    unsigned short* W1lo = (unsigned short*)((int*)wsb + 300032);
    int*   srcSorted = (int*)wsb + 304128;                         // E -> 1104128
    unsigned short* Vb   = (unsigned short*)((int*)wsb + 1104128); // N*128 us -> 4304128
    unsigned short* h1b  = (unsigned short*)((int*)wsb + 4304128); // N*128 us -> 7504128
    unsigned short* Ub   = (unsigned short*)((int*)wsb + 7504128); // N*128 us (h1b still live in k_conv2!)
    unsigned int* hRow = (unsigned int*)wsb + 10704128;            // HB*W -> 12304128
    unsigned int* hCol = (unsigned int*)wsb + 12304128;            // HB*W -> 13904128
    unsigned int* xb   = (unsigned int*)wsb + 13904128;            // N*32 words -> 15504128

    const int* row  = ei;
    const int* col  = ei + E;
    const int* srcA = eli;
    const int* dstA = eli + Q;

    k_pre<<<nHist + nXb + 161, 256, 0, stream>>>(
        row, col, hRow, hCol, x, xb, W1, W2, Wc1, b2, bc1,
        UVhi, UVlo, W1hi, W1lo, buv, E, N, W, chunk, nHist, nXb);
    k_rs<<<rsB, 256, 0, stream>>>(hRow, hCol, dis, offs, bsum, N, W);
    k_scan2<<<1, 256, 0, stream>>>(bsum, rsB);
    k_scan3<<<(N + 255) / 256, 256, 0, stream>>>(offs, bsum, N, E);
    k_fill3<<<dim3(HB, nPass), 256, 0, stream>>>(row, col, offs, hCol, srcSorted, E, N, W, chunk);
    k_conv1<<<(N + 15) / 16, 256, 0, stream>>>(
        (const unsigned short*)xb, offs, srcSorted, dis, W1hi, W1lo, b1, h1b, N);
    k_conv2<<<(N + 31) / 32, 512, 0, stream>>>(
        h1b, offs, srcSorted, dis, UVhi, UVlo, buv, Ub, Vb, N);
    k_head<<<(Q + 15) / 16, 256, 0, stream>>>(Ub, Vb, srcA, dstA, Wc2, bc2, out, Q);
}